// Round 7
// baseline (1723.124 us; speedup 1.0000x reference)
//
#include <hip/hip_runtime.h>
#include <stdint.h>

#define T_STEPS 256
#define BATCH 64
#define DIM 1024
#define HID 1024
#define RANK 256
#define FOURH 4096
#define M1 (T_STEPS * BATCH) // 16384

typedef __bf16 bf16_t;
typedef bf16_t bf16x8 __attribute__((ext_vector_type(8)));
typedef float f32x4 __attribute__((ext_vector_type(4)));

union frag_cast { uint4 u; bf16x8 v; };

__device__ __forceinline__ bf16x8 load_frag(const unsigned short* p) {
  frag_cast c; c.u = *reinterpret_cast<const uint4*>(p); return c.v;
}
__device__ __forceinline__ unsigned short f2bf(float f) {
  union { float f; uint32_t u; } v; v.f = f;
  uint32_t u = v.u;
  return (unsigned short)((u + 0x7fffu + ((u >> 16) & 1u)) >> 16);
}
__device__ __forceinline__ float bf2f(unsigned short h) {
  union { uint32_t u; float f; } v; v.u = ((uint32_t)h) << 16; return v.f;
}
// Branch-free fast gates: v_exp + v_rcp (~1e-7 rel err, negligible vs bf16 noise).
__device__ __forceinline__ float fsig(float x) {
  return __builtin_amdgcn_rcpf(1.f + __expf(-x));
}
__device__ __forceinline__ float ftanh(float x) {
  return 1.f - 2.f * __builtin_amdgcn_rcpf(1.f + __expf(2.f * x));
}

// Pack a [K x N] logical B matrix (f32 source) into MFMA B-fragment layout:
// frag (kc, nt): lane l slot s holds B[kc*32 + (l>>4)*8 + s][nt*16 + (l&15)].
__global__ void k_pack(const float* __restrict__ src, unsigned short* __restrict__ dst,
                       int NT, int ld, int transposed) {
  int id = blockIdx.x * blockDim.x + threadIdx.x;
  int lane = id & 63;
  int fi = id >> 6; // kc*NT + nt
  int nt = fi % NT, kc = fi / NT;
  int k0 = kc * 32 + ((lane >> 4) * 8);
  int n  = nt * 16 + (lane & 15);
  unsigned short vals[8];
  if (transposed) {
    const float* p = src + (size_t)n * ld + k0;
#pragma unroll
    for (int s = 0; s < 8; ++s) vals[s] = f2bf(p[s]);
  } else {
#pragma unroll
    for (int s = 0; s < 8; ++s) vals[s] = f2bf(src[(size_t)(k0 + s) * ld + n]);
  }
  union { unsigned short u16[8]; uint4 u; } o;
#pragma unroll
  for (int s = 0; s < 8; ++s) o.u16[s] = vals[s];
  *reinterpret_cast<uint4*>(dst + (size_t)id * 8) = o.u;
}

// corr_x[j] = dia_x[j%H] - dot(u_x[j%H,:], w_x[j,:]);  bias[j] = b_x[j]+b_h[j]
__global__ void k_coef(const float* __restrict__ u_x, const float* __restrict__ w_x,
                       const float* __restrict__ dia_x,
                       const float* __restrict__ b_x, const float* __restrict__ b_h,
                       float* __restrict__ corr, float* __restrict__ bias) {
  int wv = threadIdx.x >> 6, lane = threadIdx.x & 63;
  int j = blockIdx.x * 4 + wv;
  int e = j & (HID - 1);
  const float* up = u_x + (size_t)e * RANK + lane * 4;
  const float* wp = w_x + (size_t)j * RANK + lane * 4;
  float s = up[0] * wp[0] + up[1] * wp[1] + up[2] * wp[2] + up[3] * wp[3];
#pragma unroll
  for (int off = 32; off > 0; off >>= 1) s += __shfl_xor(s, off, 64);
  if (lane == 0) {
    corr[j] = dia_x[e] - s;
    bias[j] = b_x[j] + b_h[j];
  }
}

// Tagged h-exchange init: word = (tag16 << 16) | bf16(h).
// buf0 holds h(0) with tag 0; buf1 gets sentinel tag 0xFFFF (!= any real tag).
__global__ void k_init(const float* __restrict__ h0, uint32_t* __restrict__ hbuf) {
  int i = blockIdx.x * blockDim.x + threadIdx.x; // exactly BATCH*HID threads
  hbuf[i] = (uint32_t)f2bf(h0[i]);          // tag 0 | h0
  hbuf[BATCH * HID + i] = 0xFFFF0000u;      // sentinel
}

// C[M x 64*gridDim.x] = A_f32[M x 32*KC] @ packB, store bf16.
// dia != null: C is AhT [j][d]; override C[j][d] = dia[d] when d == j % HID.
__global__ void k_gemm_a32(const float* __restrict__ A, int lda,
                           const unsigned short* __restrict__ packB, int NTtot,
                           int KC, unsigned short* __restrict__ C, int ldc,
                           const float* __restrict__ dia) {
  int w = threadIdx.x >> 6, lane = threadIdx.x & 63;
  int q = lane >> 4, ln = lane & 15;
  int m0 = blockIdx.y * 64, n0 = blockIdx.x * 64;
  int arow = m0 + w * 16 + ln;
  f32x4 acc[4] = {};
  for (int kc = 0; kc < KC; ++kc) {
    const float* ap = A + (size_t)arow * lda + kc * 32 + q * 8;
    float4 x0 = *reinterpret_cast<const float4*>(ap);
    float4 x1 = *reinterpret_cast<const float4*>(ap + 4);
    bf16x8 a;
    a[0] = (bf16_t)x0.x; a[1] = (bf16_t)x0.y; a[2] = (bf16_t)x0.z; a[3] = (bf16_t)x0.w;
    a[4] = (bf16_t)x1.x; a[5] = (bf16_t)x1.y; a[6] = (bf16_t)x1.z; a[7] = (bf16_t)x1.w;
#pragma unroll
    for (int nt = 0; nt < 4; ++nt) {
      bf16x8 b = load_frag(packB + ((size_t)(kc * NTtot + blockIdx.x * 4 + nt) * 64 + lane) * 8);
      acc[nt] = __builtin_amdgcn_mfma_f32_16x16x32_bf16(a, b, acc[nt], 0, 0, 0);
    }
  }
#pragma unroll
  for (int nt = 0; nt < 4; ++nt) {
    int ccol = n0 + nt * 16 + ln;
#pragma unroll
    for (int r = 0; r < 4; ++r) {
      int crow = m0 + w * 16 + q * 4 + r;
      float v = acc[nt][r];
      if (dia != nullptr && ccol == (crow & (HID - 1))) v = dia[ccol];
      C[(size_t)crow * ldc + ccol] = f2bf(v);
    }
  }
}

// Repack AhT [j][d] (bf16) into per-(cg,gate,kc) B-fragment layout for k_rec.
__global__ void k_packAh(const unsigned short* __restrict__ AhT, unsigned short* __restrict__ dst) {
  int id = blockIdx.x * blockDim.x + threadIdx.x;
  int lane = id & 63;
  int fi = id >> 6;        // (cg*4+g)*32 + kc
  int kc = fi & 31;
  int g  = (fi >> 5) & 3;
  int cg = fi >> 7;
  int j  = g * HID + cg * 16 + (lane & 15);
  int d0 = kc * 32 + ((lane >> 4) * 8);
  uint4 v = *reinterpret_cast<const uint4*>(AhT + (size_t)j * HID + d0);
  *reinterpret_cast<uint4*>(dst + (size_t)id * 8) = v;
}

// gx[m][j] = P[m,:] @ w_xT[:,j] + x[m][j%H]*corr[j] + bias[j], store bf16.
__global__ void k_gemm2(const unsigned short* __restrict__ P,
                        const unsigned short* __restrict__ packWx,
                        const float* __restrict__ x,
                        const float* __restrict__ corr, const float* __restrict__ bias,
                        unsigned short* __restrict__ gx) {
  int w = threadIdx.x >> 6, lane = threadIdx.x & 63;
  int q = lane >> 4, ln = lane & 15;
  int m0 = blockIdx.y * 64, n0 = blockIdx.x * 64;
  int arow = m0 + w * 16 + ln;
  f32x4 acc[4] = {};
#pragma unroll
  for (int kc = 0; kc < 8; ++kc) {
    bf16x8 a = load_frag(P + (size_t)arow * RANK + kc * 32 + q * 8);
#pragma unroll
    for (int nt = 0; nt < 4; ++nt) {
      bf16x8 b = load_frag(packWx + ((size_t)(kc * 256 + blockIdx.x * 4 + nt) * 64 + lane) * 8);
      acc[nt] = __builtin_amdgcn_mfma_f32_16x16x32_bf16(a, b, acc[nt], 0, 0, 0);
    }
  }
#pragma unroll
  for (int nt = 0; nt < 4; ++nt) {
    int j = n0 + nt * 16 + ln;
    int e = j & (HID - 1);
    float cj = corr[j], bj = bias[j];
#pragma unroll
    for (int r = 0; r < 4; ++r) {
      int m = m0 + w * 16 + q * 4 + r;
      float v = acc[nt][r] + x[(size_t)m * DIM + e] * cj + bj;
      gx[(size_t)m * FOURH + j] = f2bf(v);
    }
  }
}

// ---- k_rec v6b: STREAMED-B + full-chip grid (compile-fixed) ----
// R5 post-mortem: VGPR=120 proves named-scalar pinning ALSO spilled; the
// per-step scratch reload (per-lane replicated, volatile-ordered) was the
// invariant tax. v6 abandons pinning:
//  - B frags are read per step from pAh (read-only, L2-shared across blocks)
//    via asm-volatile flat-address global_load_dwordx4 (per-lane 64b vaddr —
//    the "s" SGPR-base form failed to compile: divergent base), software-
//    pipelined 3 groups deep with counted s_waitcnt vmcnt(8) (T4) +
//    sched_barrier(0) (rule #18).
//  - Grid 256 blocks x 256 threads (4 waves = 4 gates, one 16-col unit each):
//    ALL 256 CUs active (128 were idle since R3). Per-CU MFMA and B-stream
//    halve; stage requests/step double to 1.05M (R3 showed the request
//    ceiling is soft; this is the A/B falsifier).
// Stage/poll/publish keep the proven tag-in-data protocol (16B sc1 rounds,
// per-4B tags; publish = one 4B tagged relaxed agent atomic per thread).
#define STAGE_EACH(X) \
  X(0, r0) X(1, r1) X(2, r2) X(3, r3) X(4, r4) X(5, r5) X(6, r6) X(7, r7) \
  X(8, r8) X(9, r9) X(10, r10) X(11, r11) X(12, r12) X(13, r13) X(14, r14) X(15, r15)

__global__ __launch_bounds__(256, 1)
void k_rec(
    const unsigned short* __restrict__ pAh,
    const unsigned short* __restrict__ gx,
    const float* __restrict__ c0,
    uint32_t* __restrict__ hbuf,   // [2][BATCH][HID] tagged words
    float* __restrict__ out) {
  const int tid = threadIdx.x;
  const int g = tid >> 6, lane = tid & 63;   // wave = gate g
  const int q = lane >> 4, ln = lane & 15;
  const int blk = blockIdx.x;
  const int cg = blk & 63, bg = blk >> 6;    // 64 col-units x 4 row-groups

  // Per-lane B base: frag kc lives at Bp + kc*512 ushorts (1 KB stride).
  const unsigned short* Bp = pAh + (size_t)((cg * 4 + g) * 32) * 512 + lane * 8;

  const int rb = tid >> 4, ec = tid & 15;
  const int brow = bg * 16 + rb;
  const int e = cg * 16 + ec;
  float c = c0[brow * HID + e];

  __shared__ unsigned short hstage[16][1032];  // stride 2064B (16B-multiple)
  __shared__ float pre[4][16][17];             // +1 pad

  const size_t gx00 = (size_t)brow * FOURH + e;
  float gxv0 = bf2f(gx[gx00]);
  float gxv1 = bf2f(gx[gx00 + HID]);
  float gxv2 = bf2f(gx[gx00 + 2 * HID]);
  float gxv3 = bf2f(gx[gx00 + 3 * HID]);

  for (int t = 0; t < T_STEPS; ++t) {
    const int cur = t & 1;
    const uint32_t* hb = hbuf + (size_t)cur * (BATCH * HID);
    const unsigned tagexp = (unsigned)t;

    // Prefetch gx(t+1) first; completes under the staging poll.
    const int tn = (t + 1 < T_STEPS) ? (t + 1) : t;
    const size_t gn = ((size_t)tn * BATCH + brow) * FOURH + e;
    unsigned short n0 = gx[gn];
    unsigned short n1 = gx[gn + HID];
    unsigned short n2 = gx[gn + 2 * HID];
    unsigned short n3 = gx[gn + 3 * HID];

    // ---- Stage h(t): 16 chunks (chunk cc = row cc, granule tid). ----
    uint4 r0, r1, r2, r3, r4, r5, r6, r7, r8, r9, r10, r11, r12, r13, r14, r15;
    unsigned pend = 0xFFFFu;
    do {
#define ISSUE16(cc, rr)                                                        \
      if (pend & (1u << cc)) {                                                 \
        const uint32_t* p = hb + (((size_t)(bg * 16 + cc)) << 10) + (tid << 2);\
        asm volatile("global_load_dwordx4 %0, %1, off sc1"                     \
                     : "=&v"(rr) : "v"(p) : "memory");                         \
      }
      STAGE_EACH(ISSUE16)
#undef ISSUE16
      asm volatile("s_waitcnt vmcnt(0)" ::: "memory");
      __builtin_amdgcn_sched_barrier(0);
#define CHECK16(cc, rr)                                                        \
      if (pend & (1u << cc)) {                                                 \
        unsigned bad = ((rr.x >> 16) ^ tagexp) | ((rr.y >> 16) ^ tagexp) |     \
                       ((rr.z >> 16) ^ tagexp) | ((rr.w >> 16) ^ tagexp);      \
        if (bad == 0) {                                                        \
          unsigned lo = (rr.x & 0xffffu) | (rr.y << 16);                       \
          unsigned hi = (rr.z & 0xffffu) | (rr.w << 16);                       \
          *reinterpret_cast<unsigned long long*>(&hstage[cc][tid << 2]) =      \
              ((unsigned long long)hi << 32) | lo;                             \
          pend &= ~(1u << cc);                                                 \
        }                                                                      \
      }
      STAGE_EACH(CHECK16)
#undef CHECK16
    } while (pend);
    __syncthreads();  // hstage ready

    // ---- MFMA phase: streamed B, 8 groups of 4 frags, 3 groups in flight. --
    f32x4 acc0 = {}, acc1 = {}, acc2 = {}, acc3 = {};
    uint4 Bf0, Bf1, Bf2, Bf3, Bf4, Bf5, Bf6, Bf7, Bf8, Bf9, Bf10, Bf11,
        Bf12, Bf13, Bf14, Bf15, Bf16, Bf17, Bf18, Bf19, Bf20, Bf21, Bf22,
        Bf23, Bf24, Bf25, Bf26, Bf27, Bf28, Bf29, Bf30, Bf31;
#define BL(k)                                                                  \
    {                                                                          \
      const unsigned short* p_ = Bp + (size_t)(k) * 512;                       \
      asm volatile("global_load_dwordx4 %0, %1, off"                           \
                   : "=&v"(Bf##k) : "v"(p_));                                  \
    }
#define BLG(a, b, c2, d) BL(a) BL(b) BL(c2) BL(d)
#define VMWAIT(n)                                                              \
    asm volatile("s_waitcnt vmcnt(" #n ")" ::: "memory");                      \
    __builtin_amdgcn_sched_barrier(0);
#define MFG(k0, k1, k2, k3)                                                    \
    {                                                                          \
      bf16x8 a0_ = load_frag(&hstage[ln][(k0) * 32 + q * 8]);                  \
      bf16x8 a1_ = load_frag(&hstage[ln][(k1) * 32 + q * 8]);                  \
      bf16x8 a2_ = load_frag(&hstage[ln][(k2) * 32 + q * 8]);                  \
      bf16x8 a3_ = load_frag(&hstage[ln][(k3) * 32 + q * 8]);                  \
      VMWAIT_DISPATCH                                                          \
      frag_cast f0_, f1_, f2_, f3_;                                            \
      f0_.u = Bf##k0; f1_.u = Bf##k1; f2_.u = Bf##k2; f3_.u = Bf##k3;          \
      acc0 = __builtin_amdgcn_mfma_f32_16x16x32_bf16(a0_, f0_.v, acc0, 0, 0, 0); \
      acc1 = __builtin_amdgcn_mfma_f32_16x16x32_bf16(a1_, f1_.v, acc1, 0, 0, 0); \
      acc2 = __builtin_amdgcn_mfma_f32_16x16x32_bf16(a2_, f2_.v, acc2, 0, 0, 0); \
      acc3 = __builtin_amdgcn_mfma_f32_16x16x32_bf16(a3_, f3_.v, acc3, 0, 0, 0); \
    }
    BLG(0, 1, 2, 3) BLG(4, 5, 6, 7)
#define VMWAIT_DISPATCH VMWAIT(8)
    BLG(8, 9, 10, 11)   MFG(0, 1, 2, 3)
    BLG(12, 13, 14, 15) MFG(4, 5, 6, 7)
    BLG(16, 17, 18, 19) MFG(8, 9, 10, 11)
    BLG(20, 21, 22, 23) MFG(12, 13, 14, 15)
    BLG(24, 25, 26, 27) MFG(16, 17, 18, 19)
    BLG(28, 29, 30, 31) MFG(20, 21, 22, 23)
#undef VMWAIT_DISPATCH
#define VMWAIT_DISPATCH VMWAIT(4)
    MFG(24, 25, 26, 27)
#undef VMWAIT_DISPATCH
#define VMWAIT_DISPATCH VMWAIT(0)
    MFG(28, 29, 30, 31)
#undef VMWAIT_DISPATCH
#undef MFG
#undef BLG
#undef BL

#pragma unroll
    for (int r = 0; r < 4; ++r)
      pre[g][q * 4 + r][ln] = (acc0[r] + acc1[r]) + (acc2[r] + acc3[r]);
    __syncthreads();

    float p0 = pre[0][rb][ec] + gxv0;
    float p1 = pre[1][rb][ec] + gxv1;
    float p2 = pre[2][rb][ec] + gxv2;
    float p3 = pre[3][rb][ec] + gxv3;

    float gi = fsig(p0);
    float gf = fsig(p1);
    float go = fsig(p2);
    float gn_ = ftanh(p3);
    c = gf * c + gi * gn_;
    float hn = go * ftanh(c);

    // Publish h(t+1): ONE 4B tagged relaxed agent atomic store per thread.
    {
      uint32_t wv = (((unsigned)(t + 1)) << 16) | (uint32_t)f2bf(hn);
      __hip_atomic_store(
          hbuf + (size_t)(cur ^ 1) * (BATCH * HID) + ((size_t)brow << 10) + e,
          wv, __ATOMIC_RELAXED, __HIP_MEMORY_SCOPE_AGENT);
    }

    // out stores: never read on device; ack overlaps the next stage round.
    out[((size_t)t * BATCH + brow) * HID + e] = hn;
    if (t == T_STEPS - 1) {
      out[(size_t)T_STEPS * BATCH * HID + brow * HID + e] = hn;              // h_f
      out[(size_t)T_STEPS * BATCH * HID + BATCH * HID + brow * HID + e] = c; // c_f
    }

    gxv0 = bf2f(n0); gxv1 = bf2f(n1); gxv2 = bf2f(n2); gxv3 = bf2f(n3);
  }
}

extern "C" void kernel_launch(void* const* d_in, const int* in_sizes, int n_in,
                              void* d_out, int out_size, void* d_ws, size_t ws_size,
                              hipStream_t stream) {
  const float* x     = (const float*)d_in[0];
  const float* h0    = (const float*)d_in[1];
  const float* c0    = (const float*)d_in[2];
  const float* u_x   = (const float*)d_in[3];
  const float* u_h   = (const float*)d_in[4];
  const float* w_x   = (const float*)d_in[5];
  const float* w_h   = (const float*)d_in[6];
  const float* b_x   = (const float*)d_in[7];
  const float* b_h   = (const float*)d_in[8];
  const float* dia_x = (const float*)d_in[9];
  const float* dia_h = (const float*)d_in[10];
  float* out = (float*)d_out;
  (void)in_sizes; (void)n_in; (void)out_size; (void)ws_size;

  char* base = (char*)d_ws;
  size_t off = 0;
  auto alloc = [&](size_t bytes) -> void* {
    void* p = base + off;
    off = (off + bytes + 255) & ~(size_t)255;
    return p;
  };
  unsigned short* pUx  = (unsigned short*)alloc((size_t)32 * 16 * 64 * 8 * 2);
  unsigned short* pUhT = (unsigned short*)alloc((size_t)8 * 64 * 64 * 8 * 2);
  unsigned short* pWx  = (unsigned short*)alloc((size_t)8 * 256 * 64 * 8 * 2);
  float* corr = (float*)alloc((size_t)FOURH * 4);
  float* bias = (float*)alloc((size_t)FOURH * 4);
  uint32_t* hbufT = (uint32_t*)alloc((size_t)2 * BATCH * HID * 4);  // tagged
  unsigned short* P    = (unsigned short*)alloc((size_t)M1 * RANK * 2);
  unsigned short* AhT  = (unsigned short*)alloc((size_t)FOURH * HID * 2);
  unsigned short* pAh  = (unsigned short*)alloc((size_t)64 * 4 * 32 * 64 * 8 * 2);
  unsigned short* gx   = (unsigned short*)alloc((size_t)M1 * FOURH * 2);

  // B-operand packs (one-time, reused by GEMMs / recurrence)
  k_pack<<<128, 256, 0, stream>>>(u_x, pUx, 16, RANK, 0);   // G1 B: u_x [1024 x 256]
  k_pack<<<128, 256, 0, stream>>>(u_h, pUhT, 64, RANK, 1);  // G3 B: u_hT [256 x 1024]
  k_pack<<<512, 256, 0, stream>>>(w_x, pWx, 256, RANK, 1);  // G2 B: w_xT [256 x 4096]
  k_coef<<<1024, 256, 0, stream>>>(u_x, w_x, dia_x, b_x, b_h, corr, bias);
  k_init<<<256, 256, 0, stream>>>(h0, hbufT);
  // G1: P[16384 x 256] = X @ u_x
  k_gemm_a32<<<dim3(4, 256), 256, 0, stream>>>(x, DIM, pUx, 16, 32, P, RANK, nullptr);
  // G3: AhT[4096 x 1024] = w_h @ u_hT, diagonal overridden with dia_h
  k_gemm_a32<<<dim3(16, 64), 256, 0, stream>>>(w_h, RANK, pUhT, 64, 8, AhT, HID, dia_h);
  k_packAh<<<2048, 256, 0, stream>>>(AhT, pAh);
  // G2: gx = P @ w_xT + x*corr + bias  (bf16)
  k_gemm2<<<dim3(64, 256), 256, 0, stream>>>(P, pWx, x, corr, bias, gx);
  // Persistent recurrence (tag-in-data, streamed-B, full-chip grid)
  k_rec<<<256, 256, 0, stream>>>(pAh, gx, c0, hbufT, out);
}